// Round 17
// baseline (154.687 us; speedup 1.0000x reference)
//
#include <hip/hip_runtime.h>

// B=32, L=1024, D_MODEL=128, D_INNER=256, D_STATE=16, D_CONV=4, DT_RANK=8
// Workspace layout (float offsets):
#define WS_P     0        // p[512]
#define WS_Q     512      // q[512]
#define WS_V     1024     // v[256]
#define WS_ANEG  1280     // -exp(A_log) [256*16]
#define WS_WB    5376     // bf16 wb[48][256] (12288 ushort = 6144 floats)
#define WS_S1    11520    // [1024] fused block partials (b*32 + ch): chunk acc (incl uDsv)
#define WS_S2    12544    // [512]  k5 block partials
#define WS_SUM   13056    // per (b,ch): g[4096] | W[4096] | P[256] = 8448 floats; 1024 blocks
// end 8663808 floats ~= 34.7 MB

typedef __attribute__((ext_vector_type(8))) short bf16x8;
typedef __attribute__((ext_vector_type(4))) float f32x4;
typedef __attribute__((ext_vector_type(2))) float v2f;

__device__ __forceinline__ unsigned short f2bf(float f) {
    unsigned u = __float_as_uint(f);
    u += 0x7fff + ((u >> 16) & 1);
    return (unsigned short)(u >> 16);
}

__global__ void k0_precompute(const float* __restrict__ W_emb,
                              const float* __restrict__ b_emb,
                              const float* __restrict__ W_in,
                              const float* __restrict__ W_x,
                              const float* __restrict__ A_log,
                              const float* __restrict__ W_out,
                              const float* __restrict__ W_fc,
                              float* __restrict__ ws) {
    int idx = blockIdx.x * 256 + threadIdx.x;
    if (idx < 512) {
        float sp = 0.f, sq = 0.f;
        const float* row = W_in + idx * 128;
        for (int d = 0; d < 128; ++d) {
            float w = row[d];
            sp = fmaf(w, W_emb[d], sp);
            sq = fmaf(w, b_emb[d], sq);
        }
        ws[WS_P + idx] = sp;
        ws[WS_Q + idx] = sq;
    } else if (idx < 768) {
        int d = idx - 512;
        float s = 0.f;
        for (int e = 0; e < 128; ++e) s = fmaf(W_fc[e], W_out[e * 256 + d], s);
        ws[WS_V + d] = s;
    } else if (idx < 4864) {
        int i = idx - 768;
        ws[WS_ANEG + i] = -__expf(A_log[i]);
    } else if (idx < 17152) {
        int i = idx - 4864;            // [0, 48*256)
        int j = i >> 8, d = i & 255;
        float v = (j < 40) ? W_x[j * 256 + d] : 0.f;
        ((unsigned short*)(ws + WS_WB))[i] = f2bf(v);
    }
}

// Fused front-end + scan. Block = (b, 32-l chunk), 1024 blocks, 256 threads (t=d).
// r17: sv computed in the ILP-rich stage-1 loop and kept in a fully-unrolled
// register array sv_r[32] (thread t = d owns exactly the sv values its scan
// needs). Scan's serial loop loses 2 of 5 transcendentals + x/z ops.
__global__ __launch_bounds__(256, 4) void k_fused(
        const float* __restrict__ x,
        const float* __restrict__ conv_w,
        const float* __restrict__ conv_b,
        const float* __restrict__ W_dt,
        const float* __restrict__ b_dt,
        const float* __restrict__ Dvec,
        float* __restrict__ ws) {
    __shared__ unsigned short u_s[32 * 264];  // bf16 u rows (16B-aligned)
    __shared__ float part_s[2][32 * 48];      // MFMA K-half partials (dead during scan)
    __shared__ float bc_s[32 * 32];           // B|C per l
    __shared__ float xdb8_s[32 * 8];          // x_db[l][0:8] K-half sums
    __shared__ float x_s[36];

    const unsigned short* wb = (const unsigned short*)(ws + WS_WB);

    int t = threadIdx.x;
    int bk = blockIdx.x;
    int b = bk >> 5;
    int l0 = (bk & 31) << 5;

    if (t < 35) {
        int gi = l0 - 3 + t;
        x_s[t] = (gi >= 0) ? x[b * 1024 + gi] : 0.f;
    }

    float pd = ws[WS_P + t], qd = ws[WS_Q + t];
    float pz = ws[WS_P + 256 + t], qz = ws[WS_Q + 256 + t];
    float cw0 = conv_w[t], cw1 = conv_w[256 + t], cw2 = conv_w[512 + t], cw3 = conv_w[768 + t];
    float cb = conv_b[t], Dd = Dvec[t], vd = ws[WS_V + t];
    float wdt[8];
    #pragma unroll
    for (int r = 0; r < 8; ++r) wdt[r] = W_dt[t * 8 + r];
    float bdt = b_dt[t];
    float a0 = ws[WS_ANEG + t * 16];
    __syncthreads();

    // Stage 1: rolling-conv -> u = silu (bf16 to LDS); sv -> registers (fp32).
    float sv_r[32];
    float e0 = (l0 >= 3) ? fmaf(x_s[0], pd, qd) : 0.f;
    float e1 = (l0 >= 2) ? fmaf(x_s[1], pd, qd) : 0.f;
    float e2 = (l0 >= 1) ? fmaf(x_s[2], pd, qd) : 0.f;
    #pragma unroll
    for (int pp = 0; pp < 32; ++pp) {
        float x0 = x_s[pp + 3];
        float e = fmaf(x0, pd, qd);
        float s = fmaf(cw0, e0, cb);
        s = fmaf(cw1, e1, s);
        s = fmaf(cw2, e2, s);
        s = fmaf(cw3, e, s);
        e0 = e1; e1 = e2; e2 = e;
        float u = __fdividef(s, 1.f + __expf(-s));
        u_s[pp * 264 + t] = f2bf(u);
        float z = fmaf(x0, pz, qz);
        sv_r[pp] = __fdividef(z, 1.f + __expf(-z)) * vd;
    }
    __syncthreads();

    // Stage 2: x_db = u @ W^T via MFMA. 4 waves = 2 M-tiles x 2 K-halves.
    {
        int w = t >> 6, lane = t & 63;
        int col = lane & 15, quad = lane >> 4;
        int m0 = w >> 1;
        int ks = (w & 1) * 128;
        f32x4 acc0 = {0.f, 0.f, 0.f, 0.f};
        f32x4 acc1 = {0.f, 0.f, 0.f, 0.f};
        f32x4 acc2 = {0.f, 0.f, 0.f, 0.f};
        const unsigned short* arow = u_s + (m0 * 16 + col) * 264 + ks + quad * 8;
        const unsigned short* brow = wb + col * 256 + ks + quad * 8;
        #pragma unroll
        for (int s = 0; s < 4; ++s) {
            bf16x8 a = *(const bf16x8*)(arow + 32 * s);
            bf16x8 b0 = *(const bf16x8*)(brow + 32 * s);
            bf16x8 b1 = *(const bf16x8*)(brow + 16 * 256 + 32 * s);
            bf16x8 b2 = *(const bf16x8*)(brow + 32 * 256 + 32 * s);
            acc0 = __builtin_amdgcn_mfma_f32_16x16x32_bf16(a, b0, acc0, 0, 0, 0);
            acc1 = __builtin_amdgcn_mfma_f32_16x16x32_bf16(a, b1, acc1, 0, 0, 0);
            acc2 = __builtin_amdgcn_mfma_f32_16x16x32_bf16(a, b2, acc2, 0, 0, 0);
        }
        float* pr = part_s[w & 1] + (m0 * 16 + quad * 4) * 48 + col;
        #pragma unroll
        for (int r = 0; r < 4; ++r) {
            pr[r * 48] = acc0[r];
            pr[r * 48 + 16] = acc1[r];
            pr[r * 48 + 32] = acc2[r];
        }
    }
    __syncthreads();

    // Extraction: bc_s[l][32] = B|C; xdb8_s[l][8] = dt-rank partial sums
    {
        int pp = t >> 3;
        int j0 = (t & 7) * 4;
        #pragma unroll
        for (int j = 0; j < 4; ++j)
            bc_s[pp * 32 + j0 + j] =
                part_s[0][pp * 48 + 8 + j0 + j] + part_s[1][pp * 48 + 8 + j0 + j];
        int r = t & 7;
        xdb8_s[pp * 8 + r] = part_s[0][pp * 48 + r] + part_s[1][pp * 48 + r];
    }
    __syncthreads();

    // Scan: per l, dt/du inline -> packed-fp32 power-chain scan (n in pairs).
    v2f g2[8], W2[8];
    #pragma unroll
    for (int k = 0; k < 8; ++k) { g2[k] = (v2f){0.f, 0.f}; W2[k] = (v2f){0.f, 0.f}; }
    float F = 1.f, P = 0.f, acc = 0.f;

    #pragma unroll
    for (int l = 0; l < 32; ++l) {
        float4 X0 = *(const float4*)(xdb8_s + l * 8);
        float4 X1 = *(const float4*)(xdb8_s + l * 8 + 4);
        v2f s2 = (v2f){bdt, 0.f};
        s2 = __builtin_elementwise_fma((v2f){X0.x, X0.y}, (v2f){wdt[0], wdt[1]}, s2);
        s2 = __builtin_elementwise_fma((v2f){X0.z, X0.w}, (v2f){wdt[2], wdt[3]}, s2);
        s2 = __builtin_elementwise_fma((v2f){X1.x, X1.y}, (v2f){wdt[4], wdt[5]}, s2);
        s2 = __builtin_elementwise_fma((v2f){X1.z, X1.w}, (v2f){wdt[6], wdt[7]}, s2);
        float s = s2.x + s2.y;
        float dtv = fmaxf(s, 0.f) + __logf(1.f + __expf(-fabsf(s)));
        float uv = __uint_as_float(((unsigned)u_s[l * 264 + t]) << 16);
        float svf = sv_r[l];
        float E1 = __expf(dtv * a0);
        P += dtv;
        float duf = dtv * uv;
        F *= E1;
        float E1sq = E1 * E1;
        float Fsq = F * F;
        const float* br = bc_s + l * 32;
        float4 Ba = *(const float4*)(br);
        float4 Bb = *(const float4*)(br + 4);
        float4 Bc = *(const float4*)(br + 8);
        float4 Bd = *(const float4*)(br + 12);
        float4 Ca = *(const float4*)(br + 16);
        float4 Cb = *(const float4*)(br + 20);
        float4 Cc = *(const float4*)(br + 24);
        float4 Cd = *(const float4*)(br + 28);
        v2f p2 = (v2f){E1, E1sq};            // E1^(n+1) for n pair (0,1)
        v2f qc2 = (v2f){F * svf, Fsq * svf}; // F^(n+1)*sv for n pair (0,1)
        v2f mp = (v2f){E1sq, E1sq};
        v2f mq = (v2f){Fsq, Fsq};
        v2f duf2 = (v2f){duf, duf};
        v2f accl2 = (v2f){0.f, 0.f};
        #define K3_P(k, B2, C2) { \
            g2[k] = __builtin_elementwise_fma(p2, g2[k], duf2 * (B2)); \
            W2[k] = __builtin_elementwise_fma(qc2, (C2), W2[k]); \
            accl2 = __builtin_elementwise_fma(g2[k], (C2), accl2); \
            if (k < 7) { p2 = p2 * mp; qc2 = qc2 * mq; } }
        K3_P(0, ((v2f){Ba.x, Ba.y}), ((v2f){Ca.x, Ca.y}))
        K3_P(1, ((v2f){Ba.z, Ba.w}), ((v2f){Ca.z, Ca.w}))
        K3_P(2, ((v2f){Bb.x, Bb.y}), ((v2f){Cb.x, Cb.y}))
        K3_P(3, ((v2f){Bb.z, Bb.w}), ((v2f){Cb.z, Cb.w}))
        K3_P(4, ((v2f){Bc.x, Bc.y}), ((v2f){Cc.x, Cc.y}))
        K3_P(5, ((v2f){Bc.z, Bc.w}), ((v2f){Cc.z, Cc.w}))
        K3_P(6, ((v2f){Bd.x, Bd.y}), ((v2f){Cd.x, Cd.y}))
        K3_P(7, ((v2f){Bd.z, Bd.w}), ((v2f){Cd.z, Cd.w}))
        #undef K3_P
        // acc += sv * (accl + u*D)
        acc = fmaf(svf, accl2.x + accl2.y + uv * Dd, acc);
    }

    // summaries (rec = d*16 + n); g2[k] = (g[2k], g[2k+1])
    {
        float* sb = ws + WS_SUM + (size_t)bk * 8448;
        #pragma unroll
        for (int j = 0; j < 4; ++j) {
            *(float4*)(sb + t * 16 + 4 * j) =
                make_float4(g2[2*j].x, g2[2*j].y, g2[2*j+1].x, g2[2*j+1].y);
            *(float4*)(sb + 4096 + t * 16 + 4 * j) =
                make_float4(W2[2*j].x, W2[2*j].y, W2[2*j+1].x, W2[2*j+1].y);
        }
        sb[8192 + t] = P;
    }
    // final block reduction: reuse part_s[0] (dead) as scratch
    {
        float* red_s = part_s[0];
        red_s[t] = acc;
        __syncthreads();
        for (int st = 128; st > 0; st >>= 1) {
            if (t < st) red_s[t] += red_s[t + st];
            __syncthreads();
        }
        if (t == 0) ws[WS_S1 + bk] = red_s[0];
    }
}

// Recombine: thread = rec (b,d,n); chain h across 32 chunks using true a_n.
__global__ __launch_bounds__(256) void k5_recomb(float* __restrict__ ws) {
    __shared__ float red_s[256];
    int t = threadIdx.x;
    int i = blockIdx.x * 256 + t;
    int b = i >> 12;
    int rec = i & 4095;
    float an = ws[WS_ANEG + rec];
    float h = 0.f, hw = 0.f;
    for (int ch = 0; ch < 32; ++ch) {
        const float* sb = ws + WS_SUM + (size_t)(b * 32 + ch) * 8448;
        float gv = sb[rec];
        float Wv = sb[4096 + rec];
        float Pv = sb[8192 + (rec >> 4)];
        float E = __expf(an * Pv);
        hw = fmaf(h, Wv, hw);
        h = fmaf(E, h, gv);
    }
    red_s[t] = hw;
    __syncthreads();
    for (int st = 128; st > 0; st >>= 1) {
        if (t < st) red_s[t] += red_s[t + st];
        __syncthreads();
    }
    if (t == 0) ws[WS_S2 + blockIdx.x] = red_s[0];
}

__global__ void k4_final(const float* __restrict__ b_fc, const float* __restrict__ ws,
                         float* __restrict__ out) {
    int b = threadIdx.x;
    if (b < 32) {
        float s = 0.f;
        for (int k = 0; k < 32; ++k) s += ws[WS_S1 + b * 32 + k];
        for (int k = 0; k < 16; ++k) s += ws[WS_S2 + b * 16 + k];
        float logit = s * (1.f / 1024.f) + b_fc[0];
        out[b] = __fdividef(1.f, 1.f + __expf(-logit));
    }
}

extern "C" void kernel_launch(void* const* d_in, const int* in_sizes, int n_in,
                              void* d_out, int out_size, void* d_ws, size_t ws_size,
                              hipStream_t stream) {
    const float* x      = (const float*)d_in[0];
    const float* W_emb  = (const float*)d_in[1];
    const float* b_emb  = (const float*)d_in[2];
    const float* W_in   = (const float*)d_in[3];
    const float* conv_w = (const float*)d_in[4];
    const float* conv_b = (const float*)d_in[5];
    const float* W_x    = (const float*)d_in[6];
    const float* W_dt   = (const float*)d_in[7];
    const float* b_dt   = (const float*)d_in[8];
    const float* A_log  = (const float*)d_in[9];
    const float* Dvec   = (const float*)d_in[10];
    const float* W_out  = (const float*)d_in[11];
    const float* W_fc   = (const float*)d_in[12];
    const float* b_fc   = (const float*)d_in[13];
    float* ws = (float*)d_ws;

    k0_precompute<<<67, 256, 0, stream>>>(W_emb, b_emb, W_in, W_x, A_log, W_out, W_fc, ws);
    k_fused<<<1024, 256, 0, stream>>>(x, conv_w, conv_b, W_dt, b_dt, Dvec, ws);
    k5_recomb<<<512, 256, 0, stream>>>(ws);
    k4_final<<<1, 64, 0, stream>>>(b_fc, ws, (float*)d_out);
}

// Round 18
// 139.015 us; speedup vs baseline: 1.1127x; 1.1127x over previous
//
#include <hip/hip_runtime.h>

// B=32, L=1024, D_MODEL=128, D_INNER=256, D_STATE=16, D_CONV=4, DT_RANK=8
// Workspace layout (float offsets):
#define WS_P     0        // p[512]
#define WS_Q     512      // q[512]
#define WS_V     1024     // v[256]
#define WS_ANEG  1280     // -exp(A_log) [256*16]
#define WS_WB    5376     // bf16 wb[48][256] (12288 ushort = 6144 floats)
#define WS_S1    11520    // [1024] fused block partials (b*32 + ch): chunk acc (incl uDsv)
#define WS_S2    12544    // [512]  k5 block partials
#define WS_SUM   13056    // per (b,ch): g[4096] | W[4096] | P[256] = 8448 floats; 1024 blocks
// end 8663808 floats ~= 34.7 MB

typedef __attribute__((ext_vector_type(8))) short bf16x8;
typedef __attribute__((ext_vector_type(4))) float f32x4;
typedef __attribute__((ext_vector_type(2))) float v2f;

__device__ __forceinline__ unsigned short f2bf(float f) {
    unsigned u = __float_as_uint(f);
    u += 0x7fff + ((u >> 16) & 1);
    return (unsigned short)(u >> 16);
}

__global__ void k0_precompute(const float* __restrict__ W_emb,
                              const float* __restrict__ b_emb,
                              const float* __restrict__ W_in,
                              const float* __restrict__ W_x,
                              const float* __restrict__ A_log,
                              const float* __restrict__ W_out,
                              const float* __restrict__ W_fc,
                              float* __restrict__ ws) {
    int idx = blockIdx.x * 256 + threadIdx.x;
    if (idx < 512) {
        float sp = 0.f, sq = 0.f;
        const float* row = W_in + idx * 128;
        for (int d = 0; d < 128; ++d) {
            float w = row[d];
            sp = fmaf(w, W_emb[d], sp);
            sq = fmaf(w, b_emb[d], sq);
        }
        ws[WS_P + idx] = sp;
        ws[WS_Q + idx] = sq;
    } else if (idx < 768) {
        int d = idx - 512;
        float s = 0.f;
        for (int e = 0; e < 128; ++e) s = fmaf(W_fc[e], W_out[e * 256 + d], s);
        ws[WS_V + d] = s;
    } else if (idx < 4864) {
        int i = idx - 768;
        ws[WS_ANEG + i] = -__expf(A_log[i]);
    } else if (idx < 17152) {
        int i = idx - 4864;            // [0, 48*256)
        int j = i >> 8, d = i & 255;
        float v = (j < 40) ? W_x[j * 256 + d] : 0.f;
        ((unsigned short*)(ws + WS_WB))[i] = f2bf(v);
    }
}

// Fused front-end + scan. Block = (b, 32-l chunk), 1024 blocks, 256 threads (t=d).
// r18 = r17 structure at (256,2): 256-VGPR budget keeps sv_r[32] + scan state
// in registers (r17's (256,4) capped VGPR at 64 -> 135 MB scratch spill).
// Occupancy 2 vs 4 blocks/CU measured neutral (r12/r13), so the bound is free.
__global__ __launch_bounds__(256, 2) void k_fused(
        const float* __restrict__ x,
        const float* __restrict__ conv_w,
        const float* __restrict__ conv_b,
        const float* __restrict__ W_dt,
        const float* __restrict__ b_dt,
        const float* __restrict__ Dvec,
        float* __restrict__ ws) {
    __shared__ unsigned short u_s[32 * 264];  // bf16 u rows (16B-aligned)
    __shared__ float part_s[2][32 * 48];      // MFMA K-half partials (dead during scan)
    __shared__ float bc_s[32 * 32];           // B|C per l
    __shared__ float xdb8_s[32 * 8];          // x_db[l][0:8] K-half sums
    __shared__ float x_s[36];

    const unsigned short* wb = (const unsigned short*)(ws + WS_WB);

    int t = threadIdx.x;
    int bk = blockIdx.x;
    int b = bk >> 5;
    int l0 = (bk & 31) << 5;

    if (t < 35) {
        int gi = l0 - 3 + t;
        x_s[t] = (gi >= 0) ? x[b * 1024 + gi] : 0.f;
    }

    float pd = ws[WS_P + t], qd = ws[WS_Q + t];
    float pz = ws[WS_P + 256 + t], qz = ws[WS_Q + 256 + t];
    float cw0 = conv_w[t], cw1 = conv_w[256 + t], cw2 = conv_w[512 + t], cw3 = conv_w[768 + t];
    float cb = conv_b[t], Dd = Dvec[t], vd = ws[WS_V + t];
    float wdt[8];
    #pragma unroll
    for (int r = 0; r < 8; ++r) wdt[r] = W_dt[t * 8 + r];
    float bdt = b_dt[t];
    float a0 = ws[WS_ANEG + t * 16];
    __syncthreads();

    // Stage 1: rolling-conv -> u = silu (bf16 to LDS); sv -> registers (fp32).
    float sv_r[32];
    float e0 = (l0 >= 3) ? fmaf(x_s[0], pd, qd) : 0.f;
    float e1 = (l0 >= 2) ? fmaf(x_s[1], pd, qd) : 0.f;
    float e2 = (l0 >= 1) ? fmaf(x_s[2], pd, qd) : 0.f;
    #pragma unroll
    for (int pp = 0; pp < 32; ++pp) {
        float x0 = x_s[pp + 3];
        float e = fmaf(x0, pd, qd);
        float s = fmaf(cw0, e0, cb);
        s = fmaf(cw1, e1, s);
        s = fmaf(cw2, e2, s);
        s = fmaf(cw3, e, s);
        e0 = e1; e1 = e2; e2 = e;
        float u = __fdividef(s, 1.f + __expf(-s));
        u_s[pp * 264 + t] = f2bf(u);
        float z = fmaf(x0, pz, qz);
        sv_r[pp] = __fdividef(z, 1.f + __expf(-z)) * vd;
    }
    __syncthreads();

    // Stage 2: x_db = u @ W^T via MFMA. 4 waves = 2 M-tiles x 2 K-halves.
    {
        int w = t >> 6, lane = t & 63;
        int col = lane & 15, quad = lane >> 4;
        int m0 = w >> 1;
        int ks = (w & 1) * 128;
        f32x4 acc0 = {0.f, 0.f, 0.f, 0.f};
        f32x4 acc1 = {0.f, 0.f, 0.f, 0.f};
        f32x4 acc2 = {0.f, 0.f, 0.f, 0.f};
        const unsigned short* arow = u_s + (m0 * 16 + col) * 264 + ks + quad * 8;
        const unsigned short* brow = wb + col * 256 + ks + quad * 8;
        #pragma unroll
        for (int s = 0; s < 4; ++s) {
            bf16x8 a = *(const bf16x8*)(arow + 32 * s);
            bf16x8 b0 = *(const bf16x8*)(brow + 32 * s);
            bf16x8 b1 = *(const bf16x8*)(brow + 16 * 256 + 32 * s);
            bf16x8 b2 = *(const bf16x8*)(brow + 32 * 256 + 32 * s);
            acc0 = __builtin_amdgcn_mfma_f32_16x16x32_bf16(a, b0, acc0, 0, 0, 0);
            acc1 = __builtin_amdgcn_mfma_f32_16x16x32_bf16(a, b1, acc1, 0, 0, 0);
            acc2 = __builtin_amdgcn_mfma_f32_16x16x32_bf16(a, b2, acc2, 0, 0, 0);
        }
        float* pr = part_s[w & 1] + (m0 * 16 + quad * 4) * 48 + col;
        #pragma unroll
        for (int r = 0; r < 4; ++r) {
            pr[r * 48] = acc0[r];
            pr[r * 48 + 16] = acc1[r];
            pr[r * 48 + 32] = acc2[r];
        }
    }
    __syncthreads();

    // Extraction: bc_s[l][32] = B|C; xdb8_s[l][8] = dt-rank partial sums
    {
        int pp = t >> 3;
        int j0 = (t & 7) * 4;
        #pragma unroll
        for (int j = 0; j < 4; ++j)
            bc_s[pp * 32 + j0 + j] =
                part_s[0][pp * 48 + 8 + j0 + j] + part_s[1][pp * 48 + 8 + j0 + j];
        int r = t & 7;
        xdb8_s[pp * 8 + r] = part_s[0][pp * 48 + r] + part_s[1][pp * 48 + r];
    }
    __syncthreads();

    // Scan: per l, dt/du inline -> packed-fp32 power-chain scan (n in pairs).
    v2f g2[8], W2[8];
    #pragma unroll
    for (int k = 0; k < 8; ++k) { g2[k] = (v2f){0.f, 0.f}; W2[k] = (v2f){0.f, 0.f}; }
    float F = 1.f, P = 0.f, acc = 0.f;

    #pragma unroll
    for (int l = 0; l < 32; ++l) {
        float4 X0 = *(const float4*)(xdb8_s + l * 8);
        float4 X1 = *(const float4*)(xdb8_s + l * 8 + 4);
        v2f s2 = (v2f){bdt, 0.f};
        s2 = __builtin_elementwise_fma((v2f){X0.x, X0.y}, (v2f){wdt[0], wdt[1]}, s2);
        s2 = __builtin_elementwise_fma((v2f){X0.z, X0.w}, (v2f){wdt[2], wdt[3]}, s2);
        s2 = __builtin_elementwise_fma((v2f){X1.x, X1.y}, (v2f){wdt[4], wdt[5]}, s2);
        s2 = __builtin_elementwise_fma((v2f){X1.z, X1.w}, (v2f){wdt[6], wdt[7]}, s2);
        float s = s2.x + s2.y;
        float dtv = fmaxf(s, 0.f) + __logf(1.f + __expf(-fabsf(s)));
        float uv = __uint_as_float(((unsigned)u_s[l * 264 + t]) << 16);
        float svf = sv_r[l];
        float E1 = __expf(dtv * a0);
        P += dtv;
        float duf = dtv * uv;
        F *= E1;
        float E1sq = E1 * E1;
        float Fsq = F * F;
        const float* br = bc_s + l * 32;
        float4 Ba = *(const float4*)(br);
        float4 Bb = *(const float4*)(br + 4);
        float4 Bc = *(const float4*)(br + 8);
        float4 Bd = *(const float4*)(br + 12);
        float4 Ca = *(const float4*)(br + 16);
        float4 Cb = *(const float4*)(br + 20);
        float4 Cc = *(const float4*)(br + 24);
        float4 Cd = *(const float4*)(br + 28);
        v2f p2 = (v2f){E1, E1sq};            // E1^(n+1) for n pair (0,1)
        v2f qc2 = (v2f){F * svf, Fsq * svf}; // F^(n+1)*sv for n pair (0,1)
        v2f mp = (v2f){E1sq, E1sq};
        v2f mq = (v2f){Fsq, Fsq};
        v2f duf2 = (v2f){duf, duf};
        v2f accl2 = (v2f){0.f, 0.f};
        #define K3_P(k, B2, C2) { \
            g2[k] = __builtin_elementwise_fma(p2, g2[k], duf2 * (B2)); \
            W2[k] = __builtin_elementwise_fma(qc2, (C2), W2[k]); \
            accl2 = __builtin_elementwise_fma(g2[k], (C2), accl2); \
            if (k < 7) { p2 = p2 * mp; qc2 = qc2 * mq; } }
        K3_P(0, ((v2f){Ba.x, Ba.y}), ((v2f){Ca.x, Ca.y}))
        K3_P(1, ((v2f){Ba.z, Ba.w}), ((v2f){Ca.z, Ca.w}))
        K3_P(2, ((v2f){Bb.x, Bb.y}), ((v2f){Cb.x, Cb.y}))
        K3_P(3, ((v2f){Bb.z, Bb.w}), ((v2f){Cb.z, Cb.w}))
        K3_P(4, ((v2f){Bc.x, Bc.y}), ((v2f){Cc.x, Cc.y}))
        K3_P(5, ((v2f){Bc.z, Bc.w}), ((v2f){Cc.z, Cc.w}))
        K3_P(6, ((v2f){Bd.x, Bd.y}), ((v2f){Cd.x, Cd.y}))
        K3_P(7, ((v2f){Bd.z, Bd.w}), ((v2f){Cd.z, Cd.w}))
        #undef K3_P
        // acc += sv * (accl + u*D)
        acc = fmaf(svf, accl2.x + accl2.y + uv * Dd, acc);
    }

    // summaries (rec = d*16 + n); g2[k] = (g[2k], g[2k+1])
    {
        float* sb = ws + WS_SUM + (size_t)bk * 8448;
        #pragma unroll
        for (int j = 0; j < 4; ++j) {
            *(float4*)(sb + t * 16 + 4 * j) =
                make_float4(g2[2*j].x, g2[2*j].y, g2[2*j+1].x, g2[2*j+1].y);
            *(float4*)(sb + 4096 + t * 16 + 4 * j) =
                make_float4(W2[2*j].x, W2[2*j].y, W2[2*j+1].x, W2[2*j+1].y);
        }
        sb[8192 + t] = P;
    }
    // final block reduction: reuse part_s[0] (dead) as scratch
    {
        float* red_s = part_s[0];
        red_s[t] = acc;
        __syncthreads();
        for (int st = 128; st > 0; st >>= 1) {
            if (t < st) red_s[t] += red_s[t + st];
            __syncthreads();
        }
        if (t == 0) ws[WS_S1 + bk] = red_s[0];
    }
}

// Recombine: thread = rec (b,d,n); chain h across 32 chunks using true a_n.
__global__ __launch_bounds__(256) void k5_recomb(float* __restrict__ ws) {
    __shared__ float red_s[256];
    int t = threadIdx.x;
    int i = blockIdx.x * 256 + t;
    int b = i >> 12;
    int rec = i & 4095;
    float an = ws[WS_ANEG + rec];
    float h = 0.f, hw = 0.f;
    for (int ch = 0; ch < 32; ++ch) {
        const float* sb = ws + WS_SUM + (size_t)(b * 32 + ch) * 8448;
        float gv = sb[rec];
        float Wv = sb[4096 + rec];
        float Pv = sb[8192 + (rec >> 4)];
        float E = __expf(an * Pv);
        hw = fmaf(h, Wv, hw);
        h = fmaf(E, h, gv);
    }
    red_s[t] = hw;
    __syncthreads();
    for (int st = 128; st > 0; st >>= 1) {
        if (t < st) red_s[t] += red_s[t + st];
        __syncthreads();
    }
    if (t == 0) ws[WS_S2 + blockIdx.x] = red_s[0];
}

__global__ void k4_final(const float* __restrict__ b_fc, const float* __restrict__ ws,
                         float* __restrict__ out) {
    int b = threadIdx.x;
    if (b < 32) {
        float s = 0.f;
        for (int k = 0; k < 32; ++k) s += ws[WS_S1 + b * 32 + k];
        for (int k = 0; k < 16; ++k) s += ws[WS_S2 + b * 16 + k];
        float logit = s * (1.f / 1024.f) + b_fc[0];
        out[b] = __fdividef(1.f, 1.f + __expf(-logit));
    }
}

extern "C" void kernel_launch(void* const* d_in, const int* in_sizes, int n_in,
                              void* d_out, int out_size, void* d_ws, size_t ws_size,
                              hipStream_t stream) {
    const float* x      = (const float*)d_in[0];
    const float* W_emb  = (const float*)d_in[1];
    const float* b_emb  = (const float*)d_in[2];
    const float* W_in   = (const float*)d_in[3];
    const float* conv_w = (const float*)d_in[4];
    const float* conv_b = (const float*)d_in[5];
    const float* W_x    = (const float*)d_in[6];
    const float* W_dt   = (const float*)d_in[7];
    const float* b_dt   = (const float*)d_in[8];
    const float* A_log  = (const float*)d_in[9];
    const float* Dvec   = (const float*)d_in[10];
    const float* W_out  = (const float*)d_in[11];
    const float* W_fc   = (const float*)d_in[12];
    const float* b_fc   = (const float*)d_in[13];
    float* ws = (float*)d_ws;

    k0_precompute<<<67, 256, 0, stream>>>(W_emb, b_emb, W_in, W_x, A_log, W_out, W_fc, ws);
    k_fused<<<1024, 256, 0, stream>>>(x, conv_w, conv_b, W_dt, b_dt, Dvec, ws);
    k5_recomb<<<512, 256, 0, stream>>>(ws);
    k4_final<<<1, 64, 0, stream>>>(b_fc, ws, (float*)d_out);
}

// Round 19
// 136.034 us; speedup vs baseline: 1.1371x; 1.0219x over previous
//
#include <hip/hip_runtime.h>

// B=32, L=1024, D_MODEL=128, D_INNER=256, D_STATE=16, D_CONV=4, DT_RANK=8
// Workspace layout (float offsets):
#define WS_P     0        // p[512]
#define WS_Q     512      // q[512]
#define WS_V     1024     // v[256]
#define WS_ANEG  1280     // -exp(A_log) [256*16]
#define WS_WB    5376     // bf16 wb[48][256] (12288 ushort = 6144 floats)
#define WS_S1    11520    // [512] fused block partials (b*16 + ch)
#define WS_S2    12032    // [512] k5 block partials
#define WS_SUM   12544    // per (b,ch): g[4096] | W[4096] | P[256] = 8448 floats; 512 blocks
// end 4337920 floats ~= 17.4 MB

typedef __attribute__((ext_vector_type(8))) short bf16x8;
typedef __attribute__((ext_vector_type(4))) float f32x4;
typedef __attribute__((ext_vector_type(2))) float v2f;

__device__ __forceinline__ unsigned short f2bf(float f) {
    unsigned u = __float_as_uint(f);
    u += 0x7fff + ((u >> 16) & 1);
    return (unsigned short)(u >> 16);
}

__global__ void k0_precompute(const float* __restrict__ W_emb,
                              const float* __restrict__ b_emb,
                              const float* __restrict__ W_in,
                              const float* __restrict__ W_x,
                              const float* __restrict__ A_log,
                              const float* __restrict__ W_out,
                              const float* __restrict__ W_fc,
                              float* __restrict__ ws) {
    int idx = blockIdx.x * 256 + threadIdx.x;
    if (idx < 512) {
        float sp = 0.f, sq = 0.f;
        const float* row = W_in + idx * 128;
        for (int d = 0; d < 128; ++d) {
            float w = row[d];
            sp = fmaf(w, W_emb[d], sp);
            sq = fmaf(w, b_emb[d], sq);
        }
        ws[WS_P + idx] = sp;
        ws[WS_Q + idx] = sq;
    } else if (idx < 768) {
        int d = idx - 512;
        float s = 0.f;
        for (int e = 0; e < 128; ++e) s = fmaf(W_fc[e], W_out[e * 256 + d], s);
        ws[WS_V + d] = s;
    } else if (idx < 4864) {
        int i = idx - 768;
        ws[WS_ANEG + i] = -__expf(A_log[i]);
    } else if (idx < 17152) {
        int i = idx - 4864;            // [0, 48*256)
        int j = i >> 8, d = i & 255;
        float v = (j < 40) ? W_x[j * 256 + d] : 0.f;
        ((unsigned short*)(ws + WS_WB))[i] = f2bf(v);
    }
}

// Fused front-end + scan. Block = (b, 64-l chunk) as TWO 32-l subtiles run
// sequentially with scan state (F,P,g2,W2,acc) carried in registers — bit-
// identical to one 64-l chunk. Grid 512 = exactly 2 blocks/CU; summaries and
// k5 work halve vs the 32-l version. (256,2): 256-VGPR budget, no spill
// (r17's (256,4) spilled; r12/13 proved 2 vs 4 blocks/CU neutral).
__global__ __launch_bounds__(256, 2) void k_fused(
        const float* __restrict__ x,
        const float* __restrict__ conv_w,
        const float* __restrict__ conv_b,
        const float* __restrict__ W_dt,
        const float* __restrict__ b_dt,
        const float* __restrict__ Dvec,
        float* __restrict__ ws) {
    __shared__ unsigned short u_s[32 * 264];  // bf16 u rows (16B-aligned), per subtile
    __shared__ float part_s[2][32 * 48];      // MFMA K-half partials
    __shared__ float bc_s[32 * 32];           // B|C per l (subtile)
    __shared__ float xdb8_s[32 * 8];          // x_db[l][0:8] sums (subtile)
    __shared__ float x_s[68];

    const unsigned short* wb = (const unsigned short*)(ws + WS_WB);

    int t = threadIdx.x;
    int bk = blockIdx.x;
    int b = bk >> 4;
    int l0 = (bk & 15) << 6;                  // 64-l chunk base

    if (t < 67) {
        int gi = l0 - 3 + t;
        x_s[t] = (gi >= 0) ? x[b * 1024 + gi] : 0.f;
    }

    float pd = ws[WS_P + t], qd = ws[WS_Q + t];
    float pz = ws[WS_P + 256 + t], qz = ws[WS_Q + 256 + t];
    float cw0 = conv_w[t], cw1 = conv_w[256 + t], cw2 = conv_w[512 + t], cw3 = conv_w[768 + t];
    float cb = conv_b[t], Dd = Dvec[t], vd = ws[WS_V + t];
    float wdt[8];
    #pragma unroll
    for (int r = 0; r < 8; ++r) wdt[r] = W_dt[t * 8 + r];
    float bdt = b_dt[t];
    float a0 = ws[WS_ANEG + t * 16];

    // scan state carried across subtiles
    v2f g2[8], W2[8];
    #pragma unroll
    for (int k = 0; k < 8; ++k) { g2[k] = (v2f){0.f, 0.f}; W2[k] = (v2f){0.f, 0.f}; }
    float F = 1.f, P = 0.f, acc = 0.f;

    for (int ss = 0; ss < 2; ++ss) {
        int sbase = ss << 5;                  // subtile base within chunk
        __syncthreads();                      // prior scan done before u_s overwrite

        // Stage 1: rolling-conv -> u = silu (bf16 to LDS); sv -> registers.
        float sv_r[32];
        {
            int gb = l0 + sbase;
            float e0 = (gb >= 3) ? fmaf(x_s[sbase], pd, qd) : 0.f;
            float e1 = (gb >= 2) ? fmaf(x_s[sbase + 1], pd, qd) : 0.f;
            float e2 = (gb >= 1) ? fmaf(x_s[sbase + 2], pd, qd) : 0.f;
            #pragma unroll
            for (int pp = 0; pp < 32; ++pp) {
                float x0 = x_s[sbase + pp + 3];
                float e = fmaf(x0, pd, qd);
                float s = fmaf(cw0, e0, cb);
                s = fmaf(cw1, e1, s);
                s = fmaf(cw2, e2, s);
                s = fmaf(cw3, e, s);
                e0 = e1; e1 = e2; e2 = e;
                float u = __fdividef(s, 1.f + __expf(-s));
                u_s[pp * 264 + t] = f2bf(u);
                float z = fmaf(x0, pz, qz);
                sv_r[pp] = __fdividef(z, 1.f + __expf(-z)) * vd;
            }
        }
        __syncthreads();

        // Stage 2: x_db = u @ W^T via MFMA. 4 waves = 2 M-tiles x 2 K-halves.
        {
            int w = t >> 6, lane = t & 63;
            int col = lane & 15, quad = lane >> 4;
            int m0 = w >> 1;
            int ks = (w & 1) * 128;
            f32x4 acc0 = {0.f, 0.f, 0.f, 0.f};
            f32x4 acc1 = {0.f, 0.f, 0.f, 0.f};
            f32x4 acc2 = {0.f, 0.f, 0.f, 0.f};
            const unsigned short* arow = u_s + (m0 * 16 + col) * 264 + ks + quad * 8;
            const unsigned short* brow = wb + col * 256 + ks + quad * 8;
            #pragma unroll
            for (int s = 0; s < 4; ++s) {
                bf16x8 a = *(const bf16x8*)(arow + 32 * s);
                bf16x8 b0 = *(const bf16x8*)(brow + 32 * s);
                bf16x8 b1 = *(const bf16x8*)(brow + 16 * 256 + 32 * s);
                bf16x8 b2 = *(const bf16x8*)(brow + 32 * 256 + 32 * s);
                acc0 = __builtin_amdgcn_mfma_f32_16x16x32_bf16(a, b0, acc0, 0, 0, 0);
                acc1 = __builtin_amdgcn_mfma_f32_16x16x32_bf16(a, b1, acc1, 0, 0, 0);
                acc2 = __builtin_amdgcn_mfma_f32_16x16x32_bf16(a, b2, acc2, 0, 0, 0);
            }
            float* pr = part_s[w & 1] + (m0 * 16 + quad * 4) * 48 + col;
            #pragma unroll
            for (int r = 0; r < 4; ++r) {
                pr[r * 48] = acc0[r];
                pr[r * 48 + 16] = acc1[r];
                pr[r * 48 + 32] = acc2[r];
            }
        }
        __syncthreads();

        // Extraction: bc_s[l][32] = B|C; xdb8_s[l][8] = dt-rank partial sums
        {
            int pp = t >> 3;
            int j0 = (t & 7) * 4;
            #pragma unroll
            for (int j = 0; j < 4; ++j)
                bc_s[pp * 32 + j0 + j] =
                    part_s[0][pp * 48 + 8 + j0 + j] + part_s[1][pp * 48 + 8 + j0 + j];
            int r = t & 7;
            xdb8_s[pp * 8 + r] = part_s[0][pp * 48 + r] + part_s[1][pp * 48 + r];
        }
        __syncthreads();

        // Scan: per l, dt/du inline -> packed-fp32 power-chain (n in pairs).
        #pragma unroll
        for (int l = 0; l < 32; ++l) {
            float4 X0 = *(const float4*)(xdb8_s + l * 8);
            float4 X1 = *(const float4*)(xdb8_s + l * 8 + 4);
            v2f s2 = (v2f){bdt, 0.f};
            s2 = __builtin_elementwise_fma((v2f){X0.x, X0.y}, (v2f){wdt[0], wdt[1]}, s2);
            s2 = __builtin_elementwise_fma((v2f){X0.z, X0.w}, (v2f){wdt[2], wdt[3]}, s2);
            s2 = __builtin_elementwise_fma((v2f){X1.x, X1.y}, (v2f){wdt[4], wdt[5]}, s2);
            s2 = __builtin_elementwise_fma((v2f){X1.z, X1.w}, (v2f){wdt[6], wdt[7]}, s2);
            float s = s2.x + s2.y;
            float dtv = fmaxf(s, 0.f) + __logf(1.f + __expf(-fabsf(s)));
            float uv = __uint_as_float(((unsigned)u_s[l * 264 + t]) << 16);
            float svf = sv_r[l];
            float E1 = __expf(dtv * a0);
            P += dtv;
            float duf = dtv * uv;
            F *= E1;
            float E1sq = E1 * E1;
            float Fsq = F * F;
            const float* br = bc_s + l * 32;
            float4 Ba = *(const float4*)(br);
            float4 Bb = *(const float4*)(br + 4);
            float4 Bc = *(const float4*)(br + 8);
            float4 Bd = *(const float4*)(br + 12);
            float4 Ca = *(const float4*)(br + 16);
            float4 Cb = *(const float4*)(br + 20);
            float4 Cc = *(const float4*)(br + 24);
            float4 Cd = *(const float4*)(br + 28);
            v2f p2 = (v2f){E1, E1sq};            // E1^(n+1) for n pair (0,1)
            v2f qc2 = (v2f){F * svf, Fsq * svf}; // F^(n+1)*sv for n pair (0,1)
            v2f mp = (v2f){E1sq, E1sq};
            v2f mq = (v2f){Fsq, Fsq};
            v2f duf2 = (v2f){duf, duf};
            v2f accl2 = (v2f){0.f, 0.f};
            #define K3_P(k, B2, C2) { \
                g2[k] = __builtin_elementwise_fma(p2, g2[k], duf2 * (B2)); \
                W2[k] = __builtin_elementwise_fma(qc2, (C2), W2[k]); \
                accl2 = __builtin_elementwise_fma(g2[k], (C2), accl2); \
                if (k < 7) { p2 = p2 * mp; qc2 = qc2 * mq; } }
            K3_P(0, ((v2f){Ba.x, Ba.y}), ((v2f){Ca.x, Ca.y}))
            K3_P(1, ((v2f){Ba.z, Ba.w}), ((v2f){Ca.z, Ca.w}))
            K3_P(2, ((v2f){Bb.x, Bb.y}), ((v2f){Cb.x, Cb.y}))
            K3_P(3, ((v2f){Bb.z, Bb.w}), ((v2f){Cb.z, Cb.w}))
            K3_P(4, ((v2f){Bc.x, Bc.y}), ((v2f){Cc.x, Cc.y}))
            K3_P(5, ((v2f){Bc.z, Bc.w}), ((v2f){Cc.z, Cc.w}))
            K3_P(6, ((v2f){Bd.x, Bd.y}), ((v2f){Cd.x, Cd.y}))
            K3_P(7, ((v2f){Bd.z, Bd.w}), ((v2f){Cd.z, Cd.w}))
            #undef K3_P
            acc = fmaf(svf, accl2.x + accl2.y + uv * Dd, acc);
        }
    }

    // summaries (rec = d*16 + n); g2[k] = (g[2k], g[2k+1])
    {
        float* sb = ws + WS_SUM + (size_t)bk * 8448;
        #pragma unroll
        for (int j = 0; j < 4; ++j) {
            *(float4*)(sb + t * 16 + 4 * j) =
                make_float4(g2[2*j].x, g2[2*j].y, g2[2*j+1].x, g2[2*j+1].y);
            *(float4*)(sb + 4096 + t * 16 + 4 * j) =
                make_float4(W2[2*j].x, W2[2*j].y, W2[2*j+1].x, W2[2*j+1].y);
        }
        sb[8192 + t] = P;
    }
    // final block reduction: reuse part_s[0] (dead) as scratch
    {
        float* red_s = part_s[0];
        red_s[t] = acc;
        __syncthreads();
        for (int st = 128; st > 0; st >>= 1) {
            if (t < st) red_s[t] += red_s[t + st];
            __syncthreads();
        }
        if (t == 0) ws[WS_S1 + bk] = red_s[0];
    }
}

// Recombine: thread = rec (b,d,n); chain h across 16 chunks using true a_n.
__global__ __launch_bounds__(256) void k5_recomb(float* __restrict__ ws) {
    __shared__ float red_s[256];
    int t = threadIdx.x;
    int i = blockIdx.x * 256 + t;
    int b = i >> 12;
    int rec = i & 4095;
    float an = ws[WS_ANEG + rec];
    float h = 0.f, hw = 0.f;
    for (int ch = 0; ch < 16; ++ch) {
        const float* sb = ws + WS_SUM + (size_t)(b * 16 + ch) * 8448;
        float gv = sb[rec];
        float Wv = sb[4096 + rec];
        float Pv = sb[8192 + (rec >> 4)];
        float E = __expf(an * Pv);
        hw = fmaf(h, Wv, hw);
        h = fmaf(E, h, gv);
    }
    red_s[t] = hw;
    __syncthreads();
    for (int st = 128; st > 0; st >>= 1) {
        if (t < st) red_s[t] += red_s[t + st];
        __syncthreads();
    }
    if (t == 0) ws[WS_S2 + blockIdx.x] = red_s[0];
}

__global__ void k4_final(const float* __restrict__ b_fc, const float* __restrict__ ws,
                         float* __restrict__ out) {
    int b = threadIdx.x;
    if (b < 32) {
        float s = 0.f;
        for (int k = 0; k < 16; ++k) s += ws[WS_S1 + b * 16 + k];
        for (int k = 0; k < 16; ++k) s += ws[WS_S2 + b * 16 + k];
        float logit = s * (1.f / 1024.f) + b_fc[0];
        out[b] = __fdividef(1.f, 1.f + __expf(-logit));
    }
}

extern "C" void kernel_launch(void* const* d_in, const int* in_sizes, int n_in,
                              void* d_out, int out_size, void* d_ws, size_t ws_size,
                              hipStream_t stream) {
    const float* x      = (const float*)d_in[0];
    const float* W_emb  = (const float*)d_in[1];
    const float* b_emb  = (const float*)d_in[2];
    const float* W_in   = (const float*)d_in[3];
    const float* conv_w = (const float*)d_in[4];
    const float* conv_b = (const float*)d_in[5];
    const float* W_x    = (const float*)d_in[6];
    const float* W_dt   = (const float*)d_in[7];
    const float* b_dt   = (const float*)d_in[8];
    const float* A_log  = (const float*)d_in[9];
    const float* Dvec   = (const float*)d_in[10];
    const float* W_out  = (const float*)d_in[11];
    const float* W_fc   = (const float*)d_in[12];
    const float* b_fc   = (const float*)d_in[13];
    float* ws = (float*)d_ws;

    k0_precompute<<<67, 256, 0, stream>>>(W_emb, b_emb, W_in, W_x, A_log, W_out, W_fc, ws);
    k_fused<<<512, 256, 0, stream>>>(x, conv_w, conv_b, W_dt, b_dt, Dvec, ws);
    k5_recomb<<<512, 256, 0, stream>>>(ws);
    k4_final<<<1, 64, 0, stream>>>(b_fc, ws, (float*)d_out);
}